// Round 1
// baseline (311.953 us; speedup 1.0000x reference)
//
#include <hip/hip_runtime.h>
#include <hip/hip_bf16.h>
#include <stdint.h>

// Problem constants (static per reference)
#define NPW   128
#define NWIN  1024
#define EPW   2048
#define NEDGE (NWIN * EPW)   // 2097152
#define BSUBJ 32
#define TMAXW 48

typedef __bf16 bf16x8_t __attribute__((ext_vector_type(8)));
typedef float  f32x4_t  __attribute__((ext_vector_type(4)));

// ---------------- K1: fused 2-layer GIN + mean pool, one block per window ----
// LDS layout (dynamic, 100864 B):
//   B1 @ 0      : M = (A + I) as bf16 [128][128], swizzled      (32 KB)
//   B2 @ 32768  : activations (XT -> Z1 -> H1 -> H1oT -> Z2 -> H2) (32 KB)
//   B3 @ 65536  : current weight^T bf16 [out][in], swizzled     (32 KB)
//   BIAS @98304 : b1a|b1b|b2a|b2b f32                            (2 KB)
//   GP  @100352 : pooling partials f32[128]                      (512 B)
#define B1_OFF   0
#define B2_OFF   32768
#define B3_OFF   65536
#define BIAS_OFF 98304
#define GP_OFF   100352
#define K1_LDS   100864

__device__ __forceinline__ int swzb(int row, int col /* bf16 element */) {
  return row * 256 + ((col * 2) ^ ((row & 7) << 4));
}

// Stage W^T (bf16, swizzled) from a row-major [in=128][out=128] f32 matrix.
__device__ __forceinline__ void stage_wT(const float* __restrict__ wsrc, char* B3, int tid) {
  const int k = tid >> 2, o0 = (tid & 3) * 32;
  const float4* src = (const float4*)(wsrc + k * 128 + o0);
  #pragma unroll
  for (int c = 0; c < 8; ++c) {
    float4 v = src[c];
    int o = o0 + c * 4;
    *(__bf16*)(B3 + swzb(o + 0, k)) = (__bf16)v.x;
    *(__bf16*)(B3 + swzb(o + 1, k)) = (__bf16)v.y;
    *(__bf16*)(B3 + swzb(o + 2, k)) = (__bf16)v.z;
    *(__bf16*)(B3 + swzb(o + 3, k)) = (__bf16)v.w;
  }
}

// One 128x128x128 GEMM: D = A * B.  A buffer row-major [i][k] (swizzled),
// B buffer holds B^T row-major [j][k] (swizzled).  Wave 'rt' owns row tile rt.
__device__ __forceinline__ void gemm_acc(const char* Ab, const char* Bb, int lane, int rt,
                                         f32x4_t acc[8]) {
  const int rowA = rt * 16 + (lane & 15);
  const int k8 = (lane >> 4) * 8;
  const int swA = (rowA & 7) << 4;
  const int swB = ((lane & 7)) << 4;   // (ct*16 + lane&15) & 7 == lane & 7
  #pragma unroll
  for (int kk = 0; kk < 4; ++kk) {
    const int kb = (kk * 32 + k8) * 2;
    bf16x8_t af = *(const bf16x8_t*)(Ab + rowA * 256 + (kb ^ swA));
    #pragma unroll
    for (int ct = 0; ct < 8; ++ct) {
      const int rowB = ct * 16 + (lane & 15);
      bf16x8_t bv = *(const bf16x8_t*)(Bb + rowB * 256 + (kb ^ swB));
      acc[ct] = __builtin_amdgcn_mfma_f32_16x16x32_bf16(af, bv, acc[ct], 0, 0, 0);
    }
  }
}

// Write accumulators row-major (node x feature), optional bias+relu.
__device__ __forceinline__ void write_row(char* Dst, int lane, int rt, const f32x4_t acc[8],
                                          const float* bias, bool relu) {
  const int r0 = rt * 16 + (lane >> 4) * 4;
  const int c = lane & 15;
  #pragma unroll
  for (int ct = 0; ct < 8; ++ct) {
    const int col = ct * 16 + c;
    const float bvl = bias ? bias[col] : 0.f;
    #pragma unroll
    for (int j = 0; j < 4; ++j) {
      float v = acc[ct][j] + bvl;
      if (relu) v = fmaxf(v, 0.f);
      *(__bf16*)(Dst + swzb(r0 + j, col)) = (__bf16)v;
    }
  }
}

// Write accumulators transposed (feature-major), packed 4x bf16 per lane.
__device__ __forceinline__ void write_transposed(char* Dst, int lane, int rt, const f32x4_t acc[8],
                                                 const float* bias, bool relu) {
  const int r0 = rt * 16 + (lane >> 4) * 4;
  const int c = lane & 15;
  #pragma unroll
  for (int ct = 0; ct < 8; ++ct) {
    const int col = ct * 16 + c;
    const float bvl = bias ? bias[col] : 0.f;
    unsigned long long pk = 0ull;
    #pragma unroll
    for (int j = 0; j < 4; ++j) {
      float v = acc[ct][j] + bvl;
      if (relu) v = fmaxf(v, 0.f);
      unsigned short u = __builtin_bit_cast(unsigned short, (__bf16)v);
      pk |= ((unsigned long long)u) << (16 * j);
    }
    *(unsigned long long*)(Dst + col * 256 + ((r0 * 2) ^ ((col & 7) << 4))) = pk;
  }
}

__global__ void __launch_bounds__(512)
gin_gnn_kernel(const float* __restrict__ x, const int* __restrict__ ei,
               const float* __restrict__ w1a, const float* __restrict__ b1a,
               const float* __restrict__ w1b, const float* __restrict__ b1b,
               const float* __restrict__ w2a, const float* __restrict__ b2a,
               const float* __restrict__ w2b, const float* __restrict__ b2b,
               float* __restrict__ g_out) {
  extern __shared__ __align__(16) char sm[];
  const int w = blockIdx.x;
  const int tid = threadIdx.x;
  const int lane = tid & 63;
  const int wv = tid >> 6;   // wave id 0..7 = row tile

  unsigned* M32 = (unsigned*)(sm + B1_OFF);
  float* gp = (float*)(sm + GP_OFF);
  float* biasb = (float*)(sm + BIAS_OFF);
  char* B1 = sm + B1_OFF;
  char* B2 = sm + B2_OFF;
  char* B3 = sm + B3_OFF;

  // zero M (u16 counts packed in u32) and pooling partials
  #pragma unroll
  for (int i = tid; i < 8192; i += 512) M32[i] = 0u;
  if (tid < 128) gp[tid] = 0.f;
  __syncthreads();

  // edge counts: M[dst][src] += 1 (one atomic per edge)
  {
    const int base = w * EPW;
    #pragma unroll
    for (int rr = 0; rr < 4; ++rr) {
      const int e = base + tid + rr * 512;
      const int s = ei[e] & 127;
      const int d = ei[NEDGE + e] & 127;
      atomicAdd(&M32[(d << 6) + (s >> 1)], 1u << ((s & 1) * 16));
    }
  }
  // stage X^T (feature-major) bf16 swizzled into B2
  {
    const int i = tid >> 2, f0 = (tid & 3) * 32;
    const float4* src = (const float4*)(x + ((size_t)w * 128 + i) * 128 + f0);
    #pragma unroll
    for (int c = 0; c < 8; ++c) {
      float4 v = src[c];
      const int f = f0 + c * 4;
      *(__bf16*)(B2 + swzb(f + 0, i)) = (__bf16)v.x;
      *(__bf16*)(B2 + swzb(f + 1, i)) = (__bf16)v.y;
      *(__bf16*)(B2 + swzb(f + 2, i)) = (__bf16)v.z;
      *(__bf16*)(B2 + swzb(f + 3, i)) = (__bf16)v.w;
    }
  }
  // stage biases (b1a|b1b|b2a|b2b)
  {
    const float* bp = (tid < 128) ? b1a : (tid < 256) ? b1b : (tid < 384) ? b2a : b2b;
    biasb[tid] = bp[tid & 127];
  }
  // stage W1a^T while B3 is free
  stage_wT(w1a, B3, tid);
  __syncthreads();

  // convert M counts -> bf16 (M + I), in place, swizzled
  {
    unsigned mv[16];
    #pragma unroll
    for (int c = 0; c < 16; ++c) mv[c] = M32[tid * 16 + c];
    __syncthreads();
    #pragma unroll
    for (int c = 0; c < 16; ++c) {
      const int idx = tid * 16 + c;
      const int d = idx >> 6;
      const int s0 = (idx & 63) * 2;
      unsigned c0 = mv[c] & 0xffffu, c1 = mv[c] >> 16;
      if (d == s0) ++c0;
      if (d == s0 + 1) ++c1;
      const unsigned short p0 = __builtin_bit_cast(unsigned short, (__bf16)(float)c0);
      const unsigned short p1 = __builtin_bit_cast(unsigned short, (__bf16)(float)c1);
      *(unsigned*)(B1 + d * 256 + ((s0 * 2) ^ ((d & 7) << 4))) = (unsigned)p0 | ((unsigned)p1 << 16);
    }
  }
  __syncthreads();

  f32x4_t acc[8];
  #define ZACC() { _Pragma("unroll") for (int q = 0; q < 8; ++q) acc[q] = (f32x4_t){0.f,0.f,0.f,0.f}; }

  // G1: Z1 = (A+I) @ X
  ZACC(); gemm_acc(B1, B2, lane, wv, acc); __syncthreads();
  write_row(B2, lane, wv, acc, nullptr, false); __syncthreads();
  // G2: H1 = relu(Z1 @ W1a + b1a)
  ZACC(); gemm_acc(B2, B3, lane, wv, acc); __syncthreads();
  write_row(B2, lane, wv, acc, biasb + 0, true);
  stage_wT(w1b, B3, tid); __syncthreads();
  // G3: H1o = relu(H1 @ W1b + b1b)  -> stored transposed
  ZACC(); gemm_acc(B2, B3, lane, wv, acc); __syncthreads();
  write_transposed(B2, lane, wv, acc, biasb + 128, true);
  stage_wT(w2a, B3, tid); __syncthreads();
  // G4: Z2 = (A+I) @ H1o
  ZACC(); gemm_acc(B1, B2, lane, wv, acc); __syncthreads();
  write_row(B2, lane, wv, acc, nullptr, false); __syncthreads();
  // G5: H2 = relu(Z2 @ W2a + b2a)
  ZACC(); gemm_acc(B2, B3, lane, wv, acc); __syncthreads();
  write_row(B2, lane, wv, acc, biasb + 256, true);
  stage_wT(w2b, B3, tid); __syncthreads();
  // G6: H2o = relu(H2 @ W2b + b2b), fused mean pool over nodes
  ZACC(); gemm_acc(B2, B3, lane, wv, acc);
  {
    const int c = lane & 15;
    #pragma unroll
    for (int ct = 0; ct < 8; ++ct) {
      const int col = ct * 16 + c;
      const float bvl = biasb[384 + col];
      float s = 0.f;
      #pragma unroll
      for (int j = 0; j < 4; ++j) s += fmaxf(acc[ct][j] + bvl, 0.f);
      s += __shfl_xor(s, 16);
      s += __shfl_xor(s, 32);
      if (lane < 16) atomicAdd(&gp[col], s);
    }
  }
  __syncthreads();
  if (tid < 128) g_out[(size_t)w * 128 + tid] = gp[tid] * (1.f / 128.f);
}

// ---------------- K2: GX[subj][pos][o] = g[w] . wih[o] + bih[o] -------------
__global__ void __launch_bounds__(384)
gx_kernel(const float* __restrict__ g, const float* __restrict__ wih,
          const float* __restrict__ bih, const int* __restrict__ lengths,
          float* __restrict__ GX) {
  __shared__ float gt[16][128];
  __shared__ int sps[16], spp[16];
  const int w0 = blockIdx.x * 16;
  const int tid = threadIdx.x;
  for (int i = tid; i < 2048; i += 384) gt[i >> 7][i & 127] = g[(size_t)w0 * 128 + i];
  if (tid < 16) {
    const int w = w0 + tid;
    int s = 0, start = 0;
    #pragma unroll 1
    for (int b = 0; b < BSUBJ; ++b) {
      const int L = lengths[b];
      if (w >= start + L) { start += L; ++s; } else break;
    }
    sps[tid] = s;
    spp[tid] = w - start;
  }
  __syncthreads();
  const int o = tid;  // 0..383
  float accw[16];
  #pragma unroll
  for (int i = 0; i < 16; ++i) accw[i] = 0.f;
  for (int k0 = 0; k0 < 128; k0 += 4) {
    const float4 wv = *(const float4*)(wih + (size_t)o * 128 + k0);
    #pragma unroll
    for (int ww = 0; ww < 16; ++ww)
      accw[ww] += wv.x * gt[ww][k0] + wv.y * gt[ww][k0 + 1] +
                  wv.z * gt[ww][k0 + 2] + wv.w * gt[ww][k0 + 3];
  }
  const float bo = bih[o];
  #pragma unroll
  for (int ww = 0; ww < 16; ++ww)
    GX[((size_t)sps[ww] * TMAXW + spp[ww]) * 384 + o] = accw[ww] + bo;
}

// ---------------- K3: masked GRU scan, one subject per block ----------------
__global__ void __launch_bounds__(384)
gru_kernel(const float* __restrict__ GX, const float* __restrict__ whh,
           const float* __restrict__ bhh, const float* __restrict__ wout,
           const float* __restrict__ bout, const int* __restrict__ lengths,
           float* __restrict__ outp) {
  __shared__ float hb[128], rb[128], zb[128], nb[128];
  const int b = blockIdx.x;
  const int o = threadIdx.x;   // output row of whh (gate-major: r 0..127, z 128..255, n 256..383)
  const int lane = o & 63;

  // whh row o in f32 registers (full precision)
  float wrf[128];
  {
    const float* wr = whh + (size_t)o * 128;
    #pragma unroll
    for (int q = 0; q < 32; ++q) {
      float4 v = ((const float4*)wr)[q];
      wrf[4 * q + 0] = v.x; wrf[4 * q + 1] = v.y;
      wrf[4 * q + 2] = v.z; wrf[4 * q + 3] = v.w;
    }
  }
  if (o < 128) hb[o] = 0.f;
  const float bho = bhh[o];
  const float wouto = (o < 128) ? wout[o] : 0.f;
  const int len = lengths[b];
  __syncthreads();

  for (int t = 0; t < len; ++t) {
    const float2 hv = *(const float2*)(hb + 2 * lane);  // lane l: h[2l], h[2l+1]
    float acc = 0.f;
    #pragma unroll
    for (int k2 = 0; k2 < 64; ++k2) {
      const float h0 = __builtin_bit_cast(float,
          __builtin_amdgcn_readlane(__builtin_bit_cast(int, hv.x), k2));
      const float h1 = __builtin_bit_cast(float,
          __builtin_amdgcn_readlane(__builtin_bit_cast(int, hv.y), k2));
      acc = fmaf(wrf[2 * k2], h0, acc);
      acc = fmaf(wrf[2 * k2 + 1], h1, acc);
    }
    const float gh = acc + bho;                                  // includes bhh
    const float gx = GX[((size_t)b * TMAXW + t) * 384 + o];      // includes bih
    if (o < 256) {
      const float v = 1.f / (1.f + __expf(-(gx + gh)));
      if (o < 128) rb[o] = v; else zb[o - 128] = v;
    }
    __syncthreads();
    if (o >= 256) {
      const float pre = gx + rb[o - 256] * gh;   // n = tanh(nx + r*nh)
      const float e2 = __expf(-2.f * pre);
      nb[o - 256] = (1.f - e2) / (1.f + e2);
    }
    __syncthreads();
    if (o < 128) {
      const float z = zb[o];
      hb[o] = (1.f - z) * nb[o] + z * hb[o];
    }
    __syncthreads();
  }

  if (o < 128) rb[o] = hb[o] * wouto;
  __syncthreads();
  if (o == 0) {
    float s = 0.f;
    for (int f = 0; f < 128; ++f) s += rb[f];
    outp[b] = s + bout[0];
  }
}

// ---------------- host launcher ---------------------------------------------
extern "C" void kernel_launch(void* const* d_in, const int* in_sizes, int n_in,
                              void* d_out, int out_size, void* d_ws, size_t ws_size,
                              hipStream_t stream) {
  const float* x    = (const float*)d_in[0];
  const int*   ei   = (const int*)d_in[1];
  // d_in[2] = batch_idx (implied by window structure; unused)
  const int*   len  = (const int*)d_in[3];
  const float* w1a  = (const float*)d_in[4];
  const float* b1a  = (const float*)d_in[5];
  const float* w1b  = (const float*)d_in[6];
  const float* b1b  = (const float*)d_in[7];
  const float* w2a  = (const float*)d_in[8];
  const float* b2a  = (const float*)d_in[9];
  const float* w2b  = (const float*)d_in[10];
  const float* b2b  = (const float*)d_in[11];
  const float* wih  = (const float*)d_in[12];
  const float* whh  = (const float*)d_in[13];
  const float* bih  = (const float*)d_in[14];
  const float* bhh  = (const float*)d_in[15];
  const float* wout = (const float*)d_in[16];
  const float* bout = (const float*)d_in[17];

  float* g  = (float*)d_ws;                                  // 1024*128 f32 = 512 KB
  float* GX = (float*)((char*)d_ws + (size_t)NWIN * 128 * 4); // 32*48*384 f32 = 2.25 MB

  hipLaunchKernelGGL(gin_gnn_kernel, dim3(NWIN), dim3(512), K1_LDS, stream,
                     x, ei, w1a, b1a, w1b, b1b, w2a, b2a, w2b, b2b, g);
  hipLaunchKernelGGL(gx_kernel, dim3(NWIN / 16), dim3(384), 0, stream,
                     g, wih, bih, len, GX);
  hipLaunchKernelGGL(gru_kernel, dim3(BSUBJ), dim3(384), 0, stream,
                     GX, whh, bhh, wout, bout, len, (float*)d_out);
}